// Round 1
// baseline (856.266 us; speedup 1.0000x reference)
//
#include <hip/hip_runtime.h>

#define N_NODES 100000
#define N_EDGES 1600000
#define NFEAT   256
#define NHID    128
#define LATENT  64

// ---------------------------------------------------------------- CSR build

__global__ __launch_bounds__(256) void k_count(const int* __restrict__ rows,
                                               int* __restrict__ deg) {
    int e = blockIdx.x * 256 + threadIdx.x;
    if (e < N_EDGES) atomicAdd(&deg[rows[e]], 1);
}

// per-block exclusive scan of deg -> row_ptr (block-local), block totals -> bsum
__global__ __launch_bounds__(512) void k_scan1(const int* __restrict__ deg,
                                               int* __restrict__ row_ptr,
                                               int* __restrict__ bsum) {
    __shared__ int s[2][512];
    int t = threadIdx.x;
    int i = blockIdx.x * 512 + t;
    int v = (i < N_NODES) ? deg[i] : 0;
    s[0][t] = v;
    __syncthreads();
    int p = 0;
    for (int off = 1; off < 512; off <<= 1) {
        int x = s[p][t];
        if (t >= off) x += s[p][t - off];
        s[p ^ 1][t] = x;
        p ^= 1;
        __syncthreads();
    }
    int incl = s[p][t];
    if (i < N_NODES) row_ptr[i] = incl - v;   // exclusive within block
    if (t == 511) bsum[blockIdx.x] = incl;    // block total
}

// exclusive scan of block sums (nb <= 256), single block
__global__ __launch_bounds__(256) void k_scan2(int* __restrict__ bsum, int nb) {
    __shared__ int s[2][256];
    int t = threadIdx.x;
    int v = (t < nb) ? bsum[t] : 0;
    s[0][t] = v;
    __syncthreads();
    int p = 0;
    for (int off = 1; off < 256; off <<= 1) {
        int x = s[p][t];
        if (t >= off) x += s[p][t - off];
        s[p ^ 1][t] = x;
        p ^= 1;
        __syncthreads();
    }
    if (t < nb) bsum[t] = s[p][t] - v;        // exclusive
}

__global__ __launch_bounds__(512) void k_scan3(int* __restrict__ row_ptr,
                                               const int* __restrict__ bsum,
                                               int* __restrict__ cursor) {
    int i = blockIdx.x * 512 + threadIdx.x;
    if (i < N_NODES) {
        int v = row_ptr[i] + bsum[blockIdx.x];
        row_ptr[i] = v;
        cursor[i] = v;
    }
    if (blockIdx.x == 0 && threadIdx.x == 0) row_ptr[N_NODES] = N_EDGES;
}

__global__ __launch_bounds__(256) void k_bucket(const int* __restrict__ rows,
                                                const int* __restrict__ cols,
                                                const float* __restrict__ w,
                                                int* __restrict__ cursor,
                                                int* __restrict__ col_s,
                                                float* __restrict__ w_s) {
    int e = blockIdx.x * 256 + threadIdx.x;
    if (e >= N_EDGES) return;
    int r = rows[e];
    int p = atomicAdd(&cursor[r], 1);
    col_s[p] = cols[e];
    w_s[p]   = w[e];
}

// ---------------------------------------------------------------- GEMM (fp32)
// C[M x 128] = A[M x K] @ B[K x 128], B/C/bias split into two 64-col halves so
// the mu/lv projection (two separate weight matrices + biases, two output
// regions) fuses into the same kernel. BM=32, BN=128, BK=32, 4x4 per thread.

#define BM 32
#define BN 128
#define BK 32

__global__ __launch_bounds__(256) void k_gemm(
    int K,
    const float* __restrict__ A, int lda,
    const float* __restrict__ B0, const float* __restrict__ B1, int ldb,
    float* __restrict__ C0, float* __restrict__ C1, int ldc,
    const float* __restrict__ bias0, const float* __restrict__ bias1)
{
    __shared__ float As[BM][BK + 1];   // +1 pad: conflict-free per-k scalar reads
    __shared__ float Bs[BK][BN];

    const int t  = threadIdx.x;
    const int m0 = blockIdx.x * BM;
    const int tc = t & 31;             // col group: cols tc*4 .. tc*4+3
    const int tr = t >> 5;             // row group: rows tr*4 .. tr*4+3

    float acc[4][4] = {};

    for (int kt = 0; kt < K; kt += BK) {
        __syncthreads();
        // stage A tile: 32 rows x 32 k, float4 per thread
        {
            int r  = t >> 3;
            int kq = (t & 7) << 2;
            float4 a4 = *(const float4*)&A[(size_t)(m0 + r) * lda + kt + kq];
            As[r][kq + 0] = a4.x;
            As[r][kq + 1] = a4.y;
            As[r][kq + 2] = a4.z;
            As[r][kq + 3] = a4.w;
        }
        // stage B tile: 32 k x 128 cols, 4x float4 per thread
        #pragma unroll
        for (int i = 0; i < 4; ++i) {
            int kr = (t >> 5) + i * 8;
            int c  = (t & 31) << 2;
            const float* Bp = (c < 64) ? (B0 + (size_t)(kt + kr) * ldb + c)
                                       : (B1 + (size_t)(kt + kr) * ldb + (c - 64));
            *(float4*)&Bs[kr][c] = *(const float4*)Bp;
        }
        __syncthreads();

        #pragma unroll
        for (int kk = 0; kk < BK; ++kk) {
            float a0 = As[tr * 4 + 0][kk];
            float a1 = As[tr * 4 + 1][kk];
            float a2 = As[tr * 4 + 2][kk];
            float a3 = As[tr * 4 + 3][kk];
            float4 b4 = *(const float4*)&Bs[kk][tc * 4];
            acc[0][0] += a0 * b4.x; acc[0][1] += a0 * b4.y; acc[0][2] += a0 * b4.z; acc[0][3] += a0 * b4.w;
            acc[1][0] += a1 * b4.x; acc[1][1] += a1 * b4.y; acc[1][2] += a1 * b4.z; acc[1][3] += a1 * b4.w;
            acc[2][0] += a2 * b4.x; acc[2][1] += a2 * b4.y; acc[2][2] += a2 * b4.z; acc[2][3] += a2 * b4.w;
            acc[3][0] += a3 * b4.x; acc[3][1] += a3 * b4.y; acc[3][2] += a3 * b4.z; acc[3][3] += a3 * b4.w;
        }
    }

    const int c = tc * 4;
    #pragma unroll
    for (int i = 0; i < 4; ++i) {
        int r = m0 + tr * 4 + i;
        float4 v = make_float4(acc[i][0], acc[i][1], acc[i][2], acc[i][3]);
        if (bias0) {
            const float* bp = (c < 64) ? (bias0 + c) : (bias1 + (c - 64));
            v.x += bp[0]; v.y += bp[1]; v.z += bp[2]; v.w += bp[3];
        }
        float* Cp = (c < 64) ? (C0 + (size_t)r * ldc + c)
                             : (C1 + (size_t)r * ldc + (c - 64));
        *(float4*)Cp = v;
    }
}

// ---------------------------------------------------------------- SpMM gather
// out[row] = relu(bias + sum_e w_e * sup[col_e]) ; one wave per row, float2/lane

__global__ __launch_bounds__(256) void k_spmm(const int* __restrict__ row_ptr,
                                              const int* __restrict__ col_s,
                                              const float* __restrict__ w_s,
                                              const float* __restrict__ sup,
                                              const float* __restrict__ bias,
                                              float* __restrict__ out) {
    int wave = threadIdx.x >> 6;
    int lane = threadIdx.x & 63;
    int row  = blockIdx.x * 4 + wave;
    if (row >= N_NODES) return;

    int beg = row_ptr[row];
    int end = row_ptr[row + 1];
    float2 acc = make_float2(0.f, 0.f);
    for (int e = beg; e < end; ++e) {
        int   c = col_s[e];
        float w = w_s[e];
        float2 v = ((const float2*)(sup + (size_t)c * NHID))[lane];
        acc.x += w * v.x;
        acc.y += w * v.y;
    }
    float o0 = acc.x + bias[lane * 2 + 0];
    float o1 = acc.y + bias[lane * 2 + 1];
    o0 = o0 > 0.f ? o0 : 0.f;
    o1 = o1 > 0.f ? o1 : 0.f;
    ((float2*)(out + (size_t)row * NHID))[lane] = make_float2(o0, o1);
}

// ---------------------------------------------------------------- launch

extern "C" void kernel_launch(void* const* d_in, const int* in_sizes, int n_in,
                              void* d_out, int out_size, void* d_ws, size_t ws_size,
                              hipStream_t stream) {
    const float* x     = (const float*)d_in[0];
    const int*   ei    = (const int*)  d_in[1];
    const float* ew    = (const float*)d_in[2];
    const float* gc1_w = (const float*)d_in[3];
    const float* gc1_b = (const float*)d_in[4];
    const float* gc2_w = (const float*)d_in[5];
    const float* gc2_b = (const float*)d_in[6];
    const float* mu_w  = (const float*)d_in[7];
    const float* mu_b  = (const float*)d_in[8];
    const float* lv_w  = (const float*)d_in[9];
    const float* lv_b  = (const float*)d_in[10];
    float* out = (float*)d_out;

    const int* rows = ei;
    const int* cols = ei + N_EDGES;

    // workspace carve-up (256B aligned)
    char* p = (char*)d_ws;
    auto alloc = [&](size_t bytes) {
        char* r = p;
        p += (bytes + 255) & ~(size_t)255;
        return r;
    };
    int*   deg     = (int*)  alloc((size_t)N_NODES * 4);
    int*   row_ptr = (int*)  alloc((size_t)(N_NODES + 1) * 4);
    int*   cursor  = (int*)  alloc((size_t)N_NODES * 4);
    int*   bsum    = (int*)  alloc(1024);
    int*   col_s   = (int*)  alloc((size_t)N_EDGES * 4);
    float* w_s     = (float*)alloc((size_t)N_EDGES * 4);
    float* bufA    = (float*)alloc((size_t)N_NODES * NHID * 4);
    float* bufB    = (float*)alloc((size_t)N_NODES * NHID * 4);
    (void)ws_size; (void)n_in; (void)in_sizes; (void)out_size;

    const int nbScan = (N_NODES + 511) / 512;   // 196

    // --- CSR build (reused by both SpMMs) ---
    hipMemsetAsync(deg, 0, (size_t)N_NODES * 4, stream);
    k_count <<<(N_EDGES + 255) / 256, 256, 0, stream>>>(rows, deg);
    k_scan1 <<<nbScan, 512, 0, stream>>>(deg, row_ptr, bsum);
    k_scan2 <<<1, 256, 0, stream>>>(bsum, nbScan);
    k_scan3 <<<nbScan, 512, 0, stream>>>(row_ptr, bsum, cursor);
    k_bucket<<<(N_EDGES + 255) / 256, 256, 0, stream>>>(rows, cols, ew, cursor, col_s, w_s);

    const int gemmGrid = N_NODES / BM;   // 3125
    // --- gc1: support = x @ W1 ; h1 = relu(spmm + b1) ---
    k_gemm<<<gemmGrid, 256, 0, stream>>>(NFEAT, x, NFEAT,
                                         gc1_w, gc1_w + 64, NHID,
                                         bufA, bufA + 64, NHID,
                                         nullptr, nullptr);
    k_spmm<<<N_NODES / 4, 256, 0, stream>>>(row_ptr, col_s, w_s, bufA, gc1_b, bufB);

    // --- gc2 ---
    k_gemm<<<gemmGrid, 256, 0, stream>>>(NHID, bufB, NHID,
                                         gc2_w, gc2_w + 64, NHID,
                                         bufA, bufA + 64, NHID,
                                         nullptr, nullptr);
    k_spmm<<<N_NODES / 4, 256, 0, stream>>>(row_ptr, col_s, w_s, bufA, gc2_b, bufB);

    // --- mu / log_var fused projection ---
    k_gemm<<<gemmGrid, 256, 0, stream>>>(NHID, bufB, NHID,
                                         mu_w, lv_w, LATENT,
                                         out, out + (size_t)N_NODES * LATENT, LATENT,
                                         mu_b, lv_b);
}

// Round 2
// 607.471 us; speedup vs baseline: 1.4096x; 1.4096x over previous
//
#include <hip/hip_runtime.h>

#define N_NODES 100000
#define N_EDGES 1600000
#define NFEAT   256
#define NHID    128
#define LATENT  64

typedef __attribute__((ext_vector_type(8))) short s16x8;
typedef __attribute__((ext_vector_type(4))) float f32x4;

__device__ __forceinline__ unsigned short f2bf(float f) {
    union { float f; unsigned u; } v; v.f = f;
    unsigned r = v.u + 0x7fffu + ((v.u >> 16) & 1u);   // RNE (finite inputs)
    return (unsigned short)(r >> 16);
}
__device__ __forceinline__ float bf2f(unsigned short s) {
    union { unsigned u; float f; } v; v.u = ((unsigned)s) << 16;
    return v.f;
}

// ---------------------------------------------------------------- CSR build

__global__ __launch_bounds__(256) void k_count(const int* __restrict__ rows,
                                               int* __restrict__ deg) {
    int e = blockIdx.x * 256 + threadIdx.x;
    if (e < N_EDGES) atomicAdd(&deg[rows[e]], 1);
}

__global__ __launch_bounds__(512) void k_scan1(const int* __restrict__ deg,
                                               int* __restrict__ row_ptr,
                                               int* __restrict__ bsum) {
    __shared__ int s[2][512];
    int t = threadIdx.x;
    int i = blockIdx.x * 512 + t;
    int v = (i < N_NODES) ? deg[i] : 0;
    s[0][t] = v;
    __syncthreads();
    int p = 0;
    for (int off = 1; off < 512; off <<= 1) {
        int x = s[p][t];
        if (t >= off) x += s[p][t - off];
        s[p ^ 1][t] = x;
        p ^= 1;
        __syncthreads();
    }
    int incl = s[p][t];
    if (i < N_NODES) row_ptr[i] = incl - v;
    if (t == 511) bsum[blockIdx.x] = incl;
}

__global__ __launch_bounds__(256) void k_scan2(int* __restrict__ bsum, int nb) {
    __shared__ int s[2][256];
    int t = threadIdx.x;
    int v = (t < nb) ? bsum[t] : 0;
    s[0][t] = v;
    __syncthreads();
    int p = 0;
    for (int off = 1; off < 256; off <<= 1) {
        int x = s[p][t];
        if (t >= off) x += s[p][t - off];
        s[p ^ 1][t] = x;
        p ^= 1;
        __syncthreads();
    }
    if (t < nb) bsum[t] = s[p][t] - v;
}

__global__ __launch_bounds__(512) void k_scan3(int* __restrict__ row_ptr,
                                               const int* __restrict__ bsum,
                                               int* __restrict__ cursor) {
    int i = blockIdx.x * 512 + threadIdx.x;
    if (i < N_NODES) {
        int v = row_ptr[i] + bsum[blockIdx.x];
        row_ptr[i] = v;
        cursor[i] = v;
    }
    if (blockIdx.x == 0 && threadIdx.x == 0) row_ptr[N_NODES] = N_EDGES;
}

__global__ __launch_bounds__(256) void k_bucket(const int* __restrict__ rows,
                                                const int* __restrict__ cols,
                                                const float* __restrict__ w,
                                                int* __restrict__ cursor,
                                                int* __restrict__ col_s,
                                                float* __restrict__ w_s) {
    int e = blockIdx.x * 256 + threadIdx.x;
    if (e >= N_EDGES) return;
    int r = rows[e];
    int p = atomicAdd(&cursor[r], 1);
    col_s[p] = cols[e];
    w_s[p]   = w[e];
}

// ------------------------------------------------------- weight pre-convert
// fp32 [K][N] (optionally split at ncol0 between B0/B1) -> bf16 in MFMA
// fragment-block order: out[((nt*K8 + kc)*16 + m)*8 + j] = B[kc*8+j][nt*16+m]

__global__ __launch_bounds__(256) void k_prep_w(
    int K, int Ntot, int ncol0, int ldb0, int ldb1,
    const float* __restrict__ B0, const float* __restrict__ B1,
    unsigned short* __restrict__ out)
{
    int c = blockIdx.x * 256 + threadIdx.x;
    int K8 = K >> 3;
    int total = (Ntot >> 4) * K8 * 16;
    if (c >= total) return;
    int m  = c & 15;
    int kc = (c >> 4) % K8;
    int nt = (c >> 4) / K8;
    int col = nt * 16 + m;
    const float* src; int ld, cc;
    if (col < ncol0) { src = B0; ld = ldb0; cc = col; }
    else             { src = B1; ld = ldb1; cc = col - ncol0; }
    s16x8 v;
    #pragma unroll
    for (int j = 0; j < 8; ++j)
        v[j] = (short)f2bf(src[(size_t)(kc * 8 + j) * ld + cc]);
    *(s16x8*)&out[(size_t)c * 8] = v;
}

// ---------------------------------------------------------------- MFMA GEMM
// C[M x 128] = A[M x K] @ B[K x 128], bf16 MFMA 16x16x32, fp32 accumulate.
// BM=32 BN=128 BK=64, 256 threads = 4 waves; wave w: row-tile w&1 (16 rows),
// col-tiles (w>>1)*4 .. +3 (64 cols). AMODE 0: A fp32 (convert in staging);
// AMODE 1: A bf16 row-major stride 128. OMODE 0: C bf16 row-major 128;
// OMODE 1: fp32 split at col 64 into C0/C1 with fused bias.

template<int AMODE, int OMODE>
__global__ __launch_bounds__(256) void k_gemm(
    int K, const float* __restrict__ A32, const unsigned short* __restrict__ A16,
    const unsigned short* __restrict__ Bpre,
    unsigned short* __restrict__ C16,
    float* __restrict__ C0, float* __restrict__ C1,
    const float* __restrict__ bias0, const float* __restrict__ bias1)
{
    __shared__ unsigned short As[2048];  // [rt2][kc8][m16][j8]
    __shared__ unsigned short Bs[8192];  // [nt8][kc8][n16][j8]

    const int t    = threadIdx.x;
    const int m0   = blockIdx.x * 32;
    const int lane = t & 63;
    const int w    = t >> 6;
    const int rt   = w & 1;
    const int ntb  = (w >> 1) * 4;
    const int fm   = lane & 15;
    const int q    = lane >> 4;
    const int K8   = K >> 3;

    f32x4 acc[4] = {};

    for (int kt = 0; kt < K; kt += 64) {
        // stage A tile: 32 rows x 64 k
        {
            int r = t >> 3, kc = t & 7;
            int lo = ((r >> 4) * 8 + kc) * 128 + (r & 15) * 8;
            if (AMODE == 0) {
                const float* g = A32 + (size_t)(m0 + r) * K + kt + kc * 8;
                float4 a = *(const float4*)g;
                float4 b = *(const float4*)(g + 4);
                s16x8 v;
                v[0] = (short)f2bf(a.x); v[1] = (short)f2bf(a.y);
                v[2] = (short)f2bf(a.z); v[3] = (short)f2bf(a.w);
                v[4] = (short)f2bf(b.x); v[5] = (short)f2bf(b.y);
                v[6] = (short)f2bf(b.z); v[7] = (short)f2bf(b.w);
                *(s16x8*)&As[lo] = v;
            } else {
                const unsigned short* g = A16 + (size_t)(m0 + r) * 128 + kt + kc * 8;
                *(s16x8*)&As[lo] = *(const s16x8*)g;
            }
        }
        // stage B tile: 64 k x 128 n (already fragment-ordered in global)
        {
            int ktc = kt >> 3;
            #pragma unroll
            for (int i = 0; i < 4; ++i) {
                int c  = t + i * 256;
                int nt = c >> 7, kc = (c >> 4) & 7, m = c & 15;
                const unsigned short* g =
                    Bpre + ((size_t)(nt * K8 + ktc + kc) * 16 + m) * 8;
                *(s16x8*)&Bs[c * 8] = *(const s16x8*)g;
            }
        }
        __syncthreads();
        #pragma unroll
        for (int kk = 0; kk < 2; ++kk) {
            int kcq = kk * 4 + q;
            s16x8 a = *(const s16x8*)&As[(rt * 8 + kcq) * 128 + fm * 8];
            #pragma unroll
            for (int i = 0; i < 4; ++i) {
                s16x8 b = *(const s16x8*)&Bs[((ntb + i) * 8 + kcq) * 128 + fm * 8];
                acc[i] = __builtin_amdgcn_mfma_f32_16x16x32_bf16(a, b, acc[i], 0, 0, 0);
            }
        }
        __syncthreads();
    }

    // epilogue: C/D layout col=lane&15, row=q*4+reg
    #pragma unroll
    for (int i = 0; i < 4; ++i) {
        int col = (ntb + i) * 16 + fm;
        #pragma unroll
        for (int j = 0; j < 4; ++j) {
            int r = m0 + rt * 16 + q * 4 + j;
            float v = acc[i][j];
            if (OMODE == 0) {
                C16[(size_t)r * 128 + col] = f2bf(v);
            } else {
                if (col < 64) C0[(size_t)r * 64 + col]      = v + bias0[col];
                else          C1[(size_t)r * 64 + col - 64] = v + bias1[col - 64];
            }
        }
    }
}

// ---------------------------------------------------------------- SpMM gather
// out[row] = relu(bias + sum_e w_e * sup[col_e]); sup/out bf16, fp32 accum.
// One wave per row, 2 bf16 feats per lane (4 B gather/lane), unroll x2.

__global__ __launch_bounds__(256) void k_spmm(const int* __restrict__ row_ptr,
                                              const int* __restrict__ col_s,
                                              const float* __restrict__ w_s,
                                              const unsigned short* __restrict__ sup,
                                              const float* __restrict__ bias,
                                              unsigned short* __restrict__ out) {
    int wave = threadIdx.x >> 6;
    int lane = threadIdx.x & 63;
    int row  = blockIdx.x * 4 + wave;
    if (row >= N_NODES) return;

    int beg = row_ptr[row];
    int end = row_ptr[row + 1];
    float a0 = 0.f, a1 = 0.f;
    int e = beg;
    for (; e + 1 < end; e += 2) {
        int   c0 = col_s[e],     c1 = col_s[e + 1];
        float w0 = w_s[e],       w1 = w_s[e + 1];
        unsigned v0 = *(const unsigned*)(sup + (size_t)c0 * NHID + lane * 2);
        unsigned v1 = *(const unsigned*)(sup + (size_t)c1 * NHID + lane * 2);
        a0 += w0 * bf2f((unsigned short)v0);
        a1 += w0 * bf2f((unsigned short)(v0 >> 16));
        a0 += w1 * bf2f((unsigned short)v1);
        a1 += w1 * bf2f((unsigned short)(v1 >> 16));
    }
    if (e < end) {
        int   c0 = col_s[e];
        float w0 = w_s[e];
        unsigned v0 = *(const unsigned*)(sup + (size_t)c0 * NHID + lane * 2);
        a0 += w0 * bf2f((unsigned short)v0);
        a1 += w0 * bf2f((unsigned short)(v0 >> 16));
    }
    float o0 = a0 + bias[lane * 2 + 0];
    float o1 = a1 + bias[lane * 2 + 1];
    o0 = o0 > 0.f ? o0 : 0.f;
    o1 = o1 > 0.f ? o1 : 0.f;
    unsigned pv = (unsigned)f2bf(o0) | ((unsigned)f2bf(o1) << 16);
    *(unsigned*)(out + (size_t)row * NHID + lane * 2) = pv;
}

// ---------------------------------------------------------------- launch

extern "C" void kernel_launch(void* const* d_in, const int* in_sizes, int n_in,
                              void* d_out, int out_size, void* d_ws, size_t ws_size,
                              hipStream_t stream) {
    const float* x     = (const float*)d_in[0];
    const int*   ei    = (const int*)  d_in[1];
    const float* ew    = (const float*)d_in[2];
    const float* gc1_w = (const float*)d_in[3];
    const float* gc1_b = (const float*)d_in[4];
    const float* gc2_w = (const float*)d_in[5];
    const float* gc2_b = (const float*)d_in[6];
    const float* mu_w  = (const float*)d_in[7];
    const float* mu_b  = (const float*)d_in[8];
    const float* lv_w  = (const float*)d_in[9];
    const float* lv_b  = (const float*)d_in[10];
    float* out = (float*)d_out;

    const int* rows = ei;
    const int* cols = ei + N_EDGES;

    char* p = (char*)d_ws;
    auto alloc = [&](size_t bytes) {
        char* r = p;
        p += (bytes + 255) & ~(size_t)255;
        return r;
    };
    int*   deg     = (int*)  alloc((size_t)N_NODES * 4);
    int*   row_ptr = (int*)  alloc((size_t)(N_NODES + 1) * 4);
    int*   cursor  = (int*)  alloc((size_t)N_NODES * 4);
    int*   bsum    = (int*)  alloc(1024);
    int*   col_s   = (int*)  alloc((size_t)N_EDGES * 4);
    float* w_s     = (float*)alloc((size_t)N_EDGES * 4);
    unsigned short* w1p    = (unsigned short*)alloc((size_t)NFEAT * NHID * 2);
    unsigned short* w2p    = (unsigned short*)alloc((size_t)NHID * NHID * 2);
    unsigned short* w3p    = (unsigned short*)alloc((size_t)NHID * NHID * 2);
    unsigned short* bufSup = (unsigned short*)alloc((size_t)N_NODES * NHID * 2);
    unsigned short* bufH   = (unsigned short*)alloc((size_t)N_NODES * NHID * 2);
    (void)ws_size; (void)n_in; (void)in_sizes; (void)out_size;

    const int nbScan = (N_NODES + 511) / 512;   // 196

    // --- CSR build (reused by both SpMMs) ---
    hipMemsetAsync(deg, 0, (size_t)N_NODES * 4, stream);
    k_count <<<(N_EDGES + 255) / 256, 256, 0, stream>>>(rows, deg);
    k_scan1 <<<nbScan, 512, 0, stream>>>(deg, row_ptr, bsum);
    k_scan2 <<<1, 256, 0, stream>>>(bsum, nbScan);
    k_scan3 <<<nbScan, 512, 0, stream>>>(row_ptr, bsum, cursor);
    k_bucket<<<(N_EDGES + 255) / 256, 256, 0, stream>>>(rows, cols, ew, cursor, col_s, w_s);

    // --- weight pre-convert to fragment-layout bf16 ---
    k_prep_w<<<16, 256, 0, stream>>>(NFEAT, NHID, NHID, NHID, NHID, gc1_w, gc1_w, w1p);
    k_prep_w<<<8, 256, 0, stream>>>(NHID, NHID, NHID, NHID, NHID, gc2_w, gc2_w, w2p);
    k_prep_w<<<8, 256, 0, stream>>>(NHID, NHID, LATENT, LATENT, LATENT, mu_w, lv_w, w3p);

    const int gemmGrid = N_NODES / 32;   // 3125

    // --- gc1 ---
    k_gemm<0, 0><<<gemmGrid, 256, 0, stream>>>(NFEAT, x, nullptr, w1p,
                                               bufSup, nullptr, nullptr, nullptr, nullptr);
    k_spmm<<<N_NODES / 4, 256, 0, stream>>>(row_ptr, col_s, w_s, bufSup, gc1_b, bufH);

    // --- gc2 ---
    k_gemm<1, 0><<<gemmGrid, 256, 0, stream>>>(NHID, nullptr, bufH, w2p,
                                               bufSup, nullptr, nullptr, nullptr, nullptr);
    k_spmm<<<N_NODES / 4, 256, 0, stream>>>(row_ptr, col_s, w_s, bufSup, gc2_b, bufH);

    // --- mu / log_var fused projection (fp32 out + bias) ---
    k_gemm<1, 1><<<gemmGrid, 256, 0, stream>>>(NHID, nullptr, bufH, w3p,
                                               nullptr, out, out + (size_t)N_NODES * LATENT,
                                               mu_b, lv_b);
}

// Round 3
// 540.910 us; speedup vs baseline: 1.5830x; 1.1231x over previous
//
#include <hip/hip_runtime.h>
#include <hip/hip_fp16.h>

#define N_NODES 100000
#define N_EDGES 1600000
#define NFEAT   256
#define NHID    128
#define LATENT  64

typedef __attribute__((ext_vector_type(8))) short s16x8;
typedef __attribute__((ext_vector_type(4))) float f32x4;

__device__ __forceinline__ unsigned short f2bf(float f) {
    union { float f; unsigned u; } v; v.f = f;
    unsigned r = v.u + 0x7fffu + ((v.u >> 16) & 1u);   // RNE (finite inputs)
    return (unsigned short)(r >> 16);
}
__device__ __forceinline__ float bf2f(unsigned short s) {
    union { unsigned u; float f; } v; v.u = ((unsigned)s) << 16;
    return v.f;
}
// edge weight in [0,1): fp16 sans sign bit = 15 bits
__device__ __forceinline__ float w15_decode(unsigned pv) {
    return __half2float(__ushort_as_half((unsigned short)(pv & 0x7fffu)));
}

// ---------------------------------------------------------------- scans

__global__ __launch_bounds__(512) void k_scan1(const int* __restrict__ deg,
                                               int* __restrict__ row_ptr,
                                               int* __restrict__ bsum) {
    __shared__ int s[2][512];
    int t = threadIdx.x;
    int i = blockIdx.x * 512 + t;
    int v = (i < N_NODES) ? deg[i] : 0;
    s[0][t] = v;
    __syncthreads();
    int p = 0;
    for (int off = 1; off < 512; off <<= 1) {
        int x = s[p][t];
        if (t >= off) x += s[p][t - off];
        s[p ^ 1][t] = x;
        p ^= 1;
        __syncthreads();
    }
    int incl = s[p][t];
    if (i < N_NODES) row_ptr[i] = incl - v;
    if (t == 511) bsum[blockIdx.x] = incl;
}

__global__ __launch_bounds__(256) void k_scan2(int* __restrict__ bsum, int nb) {
    __shared__ int s[2][256];
    int t = threadIdx.x;
    int v = (t < nb) ? bsum[t] : 0;
    s[0][t] = v;
    __syncthreads();
    int p = 0;
    for (int off = 1; off < 256; off <<= 1) {
        int x = s[p][t];
        if (t >= off) x += s[p][t - off];
        s[p ^ 1][t] = x;
        p ^= 1;
        __syncthreads();
    }
    if (t < nb) bsum[t] = s[p][t] - v;
}

__global__ __launch_bounds__(512) void k_scan3(int* __restrict__ row_ptr,
                                               const int* __restrict__ bsum,
                                               int* __restrict__ cursor) {
    int i = blockIdx.x * 512 + threadIdx.x;
    if (i < N_NODES) {
        int v = row_ptr[i] + bsum[blockIdx.x];
        row_ptr[i] = v;
        cursor[i] = v;
    }
    if (blockIdx.x == 0 && threadIdx.x == 0) row_ptr[N_NODES] = N_EDGES;
}

// ------------------------------------------------------- weight pre-convert
// fp32 [K][N] (optionally split at ncol0 between B0/B1) -> bf16 in MFMA
// fragment-block order: out[((nt*K8 + kc)*16 + m)*8 + j] = B[kc*8+j][nt*16+m]

__device__ __forceinline__ void prep_body(
    int c, int K, int Ntot, int ncol0, int ldb0, int ldb1,
    const float* __restrict__ B0, const float* __restrict__ B1,
    unsigned short* __restrict__ out)
{
    int K8 = K >> 3;
    int total = (Ntot >> 4) * K8 * 16;
    if (c >= total) return;
    int m  = c & 15;
    int kc = (c >> 4) % K8;
    int nt = (c >> 4) / K8;
    int col = nt * 16 + m;
    const float* src; int ld, cc;
    if (col < ncol0) { src = B0; ld = ldb0; cc = col; }
    else             { src = B1; ld = ldb1; cc = col - ncol0; }
    s16x8 v;
    #pragma unroll
    for (int j = 0; j < 8; ++j)
        v[j] = (short)f2bf(src[(size_t)(kc * 8 + j) * ld + cc]);
    *(s16x8*)&out[(size_t)c * 8] = v;
}

// ---------------------------------------------------------------- MFMA GEMM
// C[M x 128] = A[M x K] @ B[K x 128], bf16 MFMA 16x16x32, fp32 accumulate.
// BM=32 BN=128 BK=64, 256 threads = 4 waves. AMODE 0: A fp32 (convert while
// staging); AMODE 1: A bf16 row-major stride 128. OMODE 0: C bf16 row-major;
// OMODE 1: fp32 split at col 64 into C0/C1 with fused bias.

template<int AMODE, int OMODE>
__device__ __forceinline__ void gemm_body(
    int bid, int K,
    const float* __restrict__ A32, const unsigned short* __restrict__ A16,
    const unsigned short* __restrict__ Bpre,
    unsigned short* __restrict__ C16,
    float* __restrict__ C0, float* __restrict__ C1,
    const float* __restrict__ bias0, const float* __restrict__ bias1,
    unsigned short* As, unsigned short* Bs)
{
    const int t    = threadIdx.x;
    const int m0   = bid * 32;
    const int lane = t & 63;
    const int w    = t >> 6;
    const int rt   = w & 1;
    const int ntb  = (w >> 1) * 4;
    const int fm   = lane & 15;
    const int q    = lane >> 4;
    const int K8   = K >> 3;

    f32x4 acc[4] = {};

    for (int kt = 0; kt < K; kt += 64) {
        {
            int r = t >> 3, kc = t & 7;
            int lo = ((r >> 4) * 8 + kc) * 128 + (r & 15) * 8;
            if (AMODE == 0) {
                const float* g = A32 + (size_t)(m0 + r) * K + kt + kc * 8;
                float4 a = *(const float4*)g;
                float4 b = *(const float4*)(g + 4);
                s16x8 v;
                v[0] = (short)f2bf(a.x); v[1] = (short)f2bf(a.y);
                v[2] = (short)f2bf(a.z); v[3] = (short)f2bf(a.w);
                v[4] = (short)f2bf(b.x); v[5] = (short)f2bf(b.y);
                v[6] = (short)f2bf(b.z); v[7] = (short)f2bf(b.w);
                *(s16x8*)&As[lo] = v;
            } else {
                const unsigned short* g = A16 + (size_t)(m0 + r) * 128 + kt + kc * 8;
                *(s16x8*)&As[lo] = *(const s16x8*)g;
            }
        }
        {
            int ktc = kt >> 3;
            #pragma unroll
            for (int i = 0; i < 4; ++i) {
                int c  = t + i * 256;
                int nt = c >> 7, kc = (c >> 4) & 7, m = c & 15;
                const unsigned short* g =
                    Bpre + ((size_t)(nt * K8 + ktc + kc) * 16 + m) * 8;
                *(s16x8*)&Bs[c * 8] = *(const s16x8*)g;
            }
        }
        __syncthreads();
        #pragma unroll
        for (int kk = 0; kk < 2; ++kk) {
            int kcq = kk * 4 + q;
            s16x8 a = *(const s16x8*)&As[(rt * 8 + kcq) * 128 + fm * 8];
            #pragma unroll
            for (int i = 0; i < 4; ++i) {
                s16x8 b = *(const s16x8*)&Bs[((ntb + i) * 8 + kcq) * 128 + fm * 8];
                acc[i] = __builtin_amdgcn_mfma_f32_16x16x32_bf16(a, b, acc[i], 0, 0, 0);
            }
        }
        __syncthreads();
    }

    // epilogue: C/D layout col=lane&15, row=q*4+reg
    #pragma unroll
    for (int i = 0; i < 4; ++i) {
        int col = (ntb + i) * 16 + fm;
        #pragma unroll
        for (int j = 0; j < 4; ++j) {
            int r = m0 + rt * 16 + q * 4 + j;
            float v = acc[i][j];
            if (OMODE == 0) {
                C16[(size_t)r * 128 + col] = f2bf(v);
            } else {
                if (col < 64) C0[(size_t)r * 64 + col]      = v + bias0[col];
                else          C1[(size_t)r * 64 + col - 64] = v + bias1[col - 64];
            }
        }
    }
}

template<int AMODE, int OMODE>
__global__ __launch_bounds__(256) void k_gemm(
    int K, const float* __restrict__ A32, const unsigned short* __restrict__ A16,
    const unsigned short* __restrict__ Bpre,
    unsigned short* __restrict__ C16,
    float* __restrict__ C0, float* __restrict__ C1,
    const float* __restrict__ bias0, const float* __restrict__ bias1)
{
    __shared__ unsigned short As[2048];
    __shared__ unsigned short Bs[8192];
    gemm_body<AMODE, OMODE>(blockIdx.x, K, A32, A16, Bpre, C16, C0, C1,
                            bias0, bias1, As, Bs);
}

// ---------------------------------------------------------------- fused pre:
// degree histogram (6250 blocks) || prep w1 (16 blocks)

__global__ __launch_bounds__(256) void k_pre(
    const int* __restrict__ rows, int* __restrict__ deg,
    const float* __restrict__ gc1_w, unsigned short* __restrict__ w1p)
{
    int b = blockIdx.x;
    if (b < 6250) {
        int e = b * 256 + threadIdx.x;
        atomicAdd(&deg[rows[e]], 1);
    } else {
        prep_body((b - 6250) * 256 + threadIdx.x,
                  NFEAT, NHID, NHID, NHID, NHID, gc1_w, gc1_w, w1p);
    }
}

// ---------------------------------------------------------------- phase1:
// bucket scatter (6250 blocks, latency-bound) || gemm1 (3125 blocks,
// MFMA-bound) || prep w2/w3 (16 blocks). Bucket first: longest pole starts
// immediately; gemm backfills and the pipes overlap (m114 co-scheduling).

__global__ __launch_bounds__(256) void k_phase1(
    const int* __restrict__ rows, const int* __restrict__ cols,
    const float* __restrict__ ew, int* __restrict__ cursor,
    unsigned* __restrict__ ecw,
    const float* __restrict__ x, const unsigned short* __restrict__ w1p,
    unsigned short* __restrict__ bufSup,
    const float* __restrict__ gc2_w, unsigned short* __restrict__ w2p,
    const float* __restrict__ mu_w, const float* __restrict__ lv_w,
    unsigned short* __restrict__ w3p)
{
    __shared__ unsigned short As[2048];
    __shared__ unsigned short Bs[8192];
    int b = blockIdx.x;
    if (b < 6250) {
        int e = b * 256 + threadIdx.x;
        int r = rows[e];
        unsigned hv = (unsigned)__half_as_ushort(__float2half(ew[e]));
        unsigned pv = ((unsigned)cols[e] << 15) | (hv & 0x7fffu);
        int p = atomicAdd(&cursor[r], 1);
        ecw[p] = pv;
    } else if (b < 6250 + 3125) {
        gemm_body<0, 0>(b - 6250, NFEAT, x, nullptr, w1p,
                        bufSup, nullptr, nullptr, nullptr, nullptr, As, Bs);
    } else if (b < 6250 + 3125 + 8) {
        prep_body((b - 9375) * 256 + threadIdx.x,
                  NHID, NHID, NHID, NHID, NHID, gc2_w, gc2_w, w2p);
    } else {
        prep_body((b - 9383) * 256 + threadIdx.x,
                  NHID, NHID, LATENT, LATENT, LATENT, mu_w, lv_w, w3p);
    }
}

// ---------------------------------------------------------------- SpMM gather
// out[row] = relu(bias + sum_e w_e * sup[col_e]); sup/out bf16, fp32 accum.
// One wave per row, 2 bf16 feats/lane (4 B gather), unroll x4 for MLP.

__global__ __launch_bounds__(256) void k_spmm(const int* __restrict__ row_ptr,
                                              const unsigned* __restrict__ ecw,
                                              const unsigned short* __restrict__ sup,
                                              const float* __restrict__ bias,
                                              unsigned short* __restrict__ out) {
    int wave = threadIdx.x >> 6;
    int lane = threadIdx.x & 63;
    int row  = blockIdx.x * 4 + wave;
    if (row >= N_NODES) return;

    int beg = row_ptr[row];
    int end = row_ptr[row + 1];
    float a0 = 0.f, a1 = 0.f;
    int e  = beg;
    int n4 = beg + ((end - beg) & ~3);
    for (; e < n4; e += 4) {
        unsigned p0 = ecw[e + 0], p1 = ecw[e + 1];
        unsigned p2 = ecw[e + 2], p3 = ecw[e + 3];
        unsigned v0 = *((const unsigned*)(sup + ((size_t)(p0 >> 15)) * NHID) + lane);
        unsigned v1 = *((const unsigned*)(sup + ((size_t)(p1 >> 15)) * NHID) + lane);
        unsigned v2 = *((const unsigned*)(sup + ((size_t)(p2 >> 15)) * NHID) + lane);
        unsigned v3 = *((const unsigned*)(sup + ((size_t)(p3 >> 15)) * NHID) + lane);
        float w0 = w15_decode(p0), w1 = w15_decode(p1);
        float w2 = w15_decode(p2), w3 = w15_decode(p3);
        a0 += w0 * bf2f((unsigned short)v0);
        a1 += w0 * bf2f((unsigned short)(v0 >> 16));
        a0 += w1 * bf2f((unsigned short)v1);
        a1 += w1 * bf2f((unsigned short)(v1 >> 16));
        a0 += w2 * bf2f((unsigned short)v2);
        a1 += w2 * bf2f((unsigned short)(v2 >> 16));
        a0 += w3 * bf2f((unsigned short)v3);
        a1 += w3 * bf2f((unsigned short)(v3 >> 16));
    }
    for (; e < end; ++e) {
        unsigned p0 = ecw[e];
        unsigned v0 = *((const unsigned*)(sup + ((size_t)(p0 >> 15)) * NHID) + lane);
        float w0 = w15_decode(p0);
        a0 += w0 * bf2f((unsigned short)v0);
        a1 += w0 * bf2f((unsigned short)(v0 >> 16));
    }
    float o0 = a0 + bias[lane * 2 + 0];
    float o1 = a1 + bias[lane * 2 + 1];
    o0 = o0 > 0.f ? o0 : 0.f;
    o1 = o1 > 0.f ? o1 : 0.f;
    unsigned pv = (unsigned)f2bf(o0) | ((unsigned)f2bf(o1) << 16);
    *(unsigned*)(out + (size_t)row * NHID + lane * 2) = pv;
}

// ---------------------------------------------------------------- launch

extern "C" void kernel_launch(void* const* d_in, const int* in_sizes, int n_in,
                              void* d_out, int out_size, void* d_ws, size_t ws_size,
                              hipStream_t stream) {
    const float* x     = (const float*)d_in[0];
    const int*   ei    = (const int*)  d_in[1];
    const float* ew    = (const float*)d_in[2];
    const float* gc1_w = (const float*)d_in[3];
    const float* gc1_b = (const float*)d_in[4];
    const float* gc2_w = (const float*)d_in[5];
    const float* gc2_b = (const float*)d_in[6];
    const float* mu_w  = (const float*)d_in[7];
    const float* mu_b  = (const float*)d_in[8];
    const float* lv_w  = (const float*)d_in[9];
    const float* lv_b  = (const float*)d_in[10];
    float* out = (float*)d_out;

    const int* rows = ei;
    const int* cols = ei + N_EDGES;

    char* p = (char*)d_ws;
    auto alloc = [&](size_t bytes) {
        char* r = p;
        p += (bytes + 255) & ~(size_t)255;
        return r;
    };
    int*      deg     = (int*)     alloc((size_t)N_NODES * 4);
    int*      row_ptr = (int*)     alloc((size_t)(N_NODES + 1) * 4);
    int*      cursor  = (int*)     alloc((size_t)N_NODES * 4);
    int*      bsum    = (int*)     alloc(1024);
    unsigned* ecw     = (unsigned*)alloc((size_t)N_EDGES * 4);
    unsigned short* w1p    = (unsigned short*)alloc((size_t)NFEAT * NHID * 2);
    unsigned short* w2p    = (unsigned short*)alloc((size_t)NHID * NHID * 2);
    unsigned short* w3p    = (unsigned short*)alloc((size_t)NHID * NHID * 2);
    unsigned short* bufSup = (unsigned short*)alloc((size_t)N_NODES * NHID * 2);
    unsigned short* bufH   = (unsigned short*)alloc((size_t)N_NODES * NHID * 2);
    (void)ws_size; (void)n_in; (void)in_sizes; (void)out_size;

    const int nbScan = (N_NODES + 511) / 512;   // 196

    hipMemsetAsync(deg, 0, (size_t)N_NODES * 4, stream);
    // count || prep w1
    k_pre<<<6250 + 16, 256, 0, stream>>>(rows, deg, gc1_w, w1p);
    k_scan1<<<nbScan, 512, 0, stream>>>(deg, row_ptr, bsum);
    k_scan2<<<1, 256, 0, stream>>>(bsum, nbScan);
    k_scan3<<<nbScan, 512, 0, stream>>>(row_ptr, bsum, cursor);
    // bucket || gemm1 || prep w2/w3
    k_phase1<<<6250 + 3125 + 16, 256, 0, stream>>>(rows, cols, ew, cursor, ecw,
                                                   x, w1p, bufSup,
                                                   gc2_w, w2p, mu_w, lv_w, w3p);
    k_spmm<<<N_NODES / 4, 256, 0, stream>>>(row_ptr, ecw, bufSup, gc1_b, bufH);

    k_gemm<1, 0><<<N_NODES / 32, 256, 0, stream>>>(NHID, nullptr, bufH, w2p,
                                                   bufSup, nullptr, nullptr, nullptr, nullptr);
    k_spmm<<<N_NODES / 4, 256, 0, stream>>>(row_ptr, ecw, bufSup, gc2_b, bufH);

    k_gemm<1, 1><<<N_NODES / 32, 256, 0, stream>>>(NHID, nullptr, bufH, w3p,
                                                   nullptr, out, out + (size_t)N_NODES * LATENT,
                                                   mu_b, lv_b);
}